// Round 9
// baseline (12.103 us; speedup 1.0000x reference)
//
#include <hip/hip_runtime.h>
#include <stdint.h>

#define NQ     9
#define NW     18
#define HIMG   128
#define WIMG   128
#define HO     126
#define WO     126
#define CCH    8
#define NSITES (HO * WO)
#define MAXRAW 64
#define MAXT   4096
#define SPB    32          // sites per block
#define TPB    256         // 32 sites x 8 channels

struct Op { int type, a, b, widx; };     // 0=RX 1=RY 2=RZ 3=CNOT(a=ctrl,b=tgt)
struct OpList { int n; Op ops[MAXRAW]; };

// ---------- constexpr numpy legacy RandomState(42) (bit-exact, verified R1-R8) ----------
struct MTc {
  uint32_t key[624] {};
  int pos = 624;
  constexpr void seed(uint32_t s) {
    for (int i = 0; i < 624; ++i) {
      key[i] = s;
      s = 1812433253u * (s ^ (s >> 30)) + (uint32_t)i + 1u;
    }
    pos = 624;
  }
  constexpr uint32_t next32() {
    if (pos == 624) {
      for (int i = 0; i < 624; ++i) {
        uint32_t y = (key[i] & 0x80000000u) | (key[(i + 1) % 624] & 0x7fffffffu);
        key[i] = key[(i + 397) % 624] ^ (y >> 1) ^ ((y & 1u) ? 0x9908b0dfu : 0u);
      }
      pos = 0;
    }
    uint32_t y = key[pos++];
    y ^= y >> 11;
    y ^= (y << 7)  & 0x9d2c5680u;
    y ^= (y << 15) & 0xefc60000u;
    y ^= y >> 18;
    return y;
  }
  constexpr double rnd() {
    uint32_t a = next32() >> 5, b = next32() >> 6;
    return (a * 67108864.0 + b) / 9007199254740992.0;
  }
  constexpr uint32_t bounded32(uint32_t rng) {
    if (rng == 0) return 0;
    uint32_t mask = rng;
    mask |= mask >> 1;  mask |= mask >> 2;  mask |= mask >> 4;
    mask |= mask >> 8;  mask |= mask >> 16;
    uint32_t v = next32() & mask;
    while (v > rng) v = next32() & mask;
    return v;
  }
};

constexpr OpList build_ops() {
  OpList ol {};
  ol.n = 0;
  MTc mt {};
  mt.seed(42u);
  for (int l = 0; l < 2; ++l) {
    int i = 0;
    while (i < NQ) {
      if (mt.rnd() > 0.3) {
        int g  = (int)mt.bounded32(2);
        int wq = (int)mt.bounded32(8);
        if (ol.n < MAXRAW) { ol.ops[ol.n] = Op{g, wq, 0, l * NQ + i}; ol.n++; }
        ++i;
      } else {
        int arr[NQ] {};
        for (int t = 0; t < NQ; ++t) arr[t] = t;
        for (int k = NQ - 1; k >= 1; --k) {
          int j = (int)mt.bounded32((uint32_t)k);
          int tmp = arr[k]; arr[k] = arr[j]; arr[j] = tmp;
        }
        if (ol.n < MAXRAW) { ol.ops[ol.n] = Op{3, arr[0], arr[1], 0}; ol.n++; }
      }
    }
  }
  return ol;
}

// ---------- compile-time Heisenberg back-propagation of Z_w (verified R6-R8) ----------
struct Term { uint32_t cmask, smask, sxm, cxm; int wire, sign; };
struct TermList { int n; Term t[MAXT]; };

constexpr int kCNc[4][4] = {{0,0,3,3},{1,1,2,2},{2,2,1,1},{3,3,0,0}};
constexpr int kCNt[4][4] = {{0,1,2,3},{1,0,3,2},{1,0,3,2},{0,1,2,3}};
constexpr int kCNs[4][4] = {{1,1,1,1},{1,1,1,-1},{1,1,-1,1},{1,1,1,1}};
constexpr int kIAPn[4][4] = {{0,0,0,0},{0,0,3,2},{0,3,0,1},{0,2,1,0}};
constexpr int kIAPs[4][4] = {{0,0,0,0},{0,0,-1,1},{0,1,0,-1},{0,-1,1,0}};

constexpr void dfs(const OpList& raw, int k, uint32_t ty, int sg,
                   uint32_t cm, uint32_t sm, int wire, TermList& TL) {
  if (k < 0) {
    uint32_t sxm = 0, cxm = 0;
    for (int j = 0; j < NQ; ++j) {
      uint32_t p = (ty >> (2 * j)) & 3u;
      if (p == 2u) return;               // Y factor -> expectation 0, prune
      if (p == 1u) sxm |= 1u << j;
      if (p == 3u) cxm |= 1u << j;
    }
    if (TL.n < MAXT) {
      TL.t[TL.n].cmask = cm; TL.t[TL.n].smask = sm;
      TL.t[TL.n].sxm = sxm;  TL.t[TL.n].cxm = cxm;
      TL.t[TL.n].wire = wire; TL.t[TL.n].sign = sg;
    }
    TL.n = TL.n + 1;
    return;
  }
  Op op = raw.ops[k];
  if (op.type == 3) {
    uint32_t pc = (ty >> (2 * op.a)) & 3u;
    uint32_t pt = (ty >> (2 * op.b)) & 3u;
    uint32_t nty = ty & ~((3u << (2 * op.a)) | (3u << (2 * op.b)));
    nty |= (uint32_t)kCNc[pc][pt] << (2 * op.a);
    nty |= (uint32_t)kCNt[pc][pt] << (2 * op.b);
    dfs(raw, k - 1, nty, sg * kCNs[pc][pt], cm, sm, wire, TL);
  } else {
    int A = op.type + 1;
    uint32_t p = (ty >> (2 * op.a)) & 3u;
    if (p == 0u || p == (uint32_t)A) {
      dfs(raw, k - 1, ty, sg, cm, sm, wire, TL);
      return;
    }
    dfs(raw, k - 1, ty, sg, cm | (1u << op.widx), sm, wire, TL);
    uint32_t nty = (ty & ~(3u << (2 * op.a))) | ((uint32_t)kIAPn[A][p] << (2 * op.a));
    dfs(raw, k - 1, nty, sg * kIAPs[A][p], cm, sm | (1u << op.widx), wire, TL);
  }
}

constexpr TermList build_terms() {
  TermList TL {};
  OpList raw = build_ops();
  for (int w = 0; w < NQ; ++w)
    dfs(raw, raw.n - 1, 3u << (2 * w), 1, 0u, 0u, w, TL);
  return TL;
}

constexpr TermList kTL = build_terms();
static_assert(kTL.n <= MAXT, "Pauli term count exceeds MAXT - raise cap");
static_assert(kTL.n >= NQ, "must have at least one term per wire");
constexpr int NT = kTL.n;

// ---------- merge terms with identical final monomial (wire, sxm, cxm) ----------
struct Groups { int ng; int gid[MAXT]; int key[MAXT]; int wire[MAXT]; uint32_t sxm[MAXT], cxm[MAXT]; };
constexpr Groups build_groups() {
  Groups G {};
  for (int t = 0; t < NT; ++t) {
    int k = (kTL.t[t].wire << 18) | ((int)kTL.t[t].sxm << 9) | (int)kTL.t[t].cxm;
    int f = -1;
    for (int j = 0; j < G.ng; ++j)
      if (G.key[j] == k) { f = j; break; }
    if (f < 0) {
      f = G.ng;
      G.key[f] = k; G.wire[f] = kTL.t[t].wire;
      G.sxm[f] = kTL.t[t].sxm; G.cxm[f] = kTL.t[t].cxm;
      G.ng = G.ng + 1;
    }
    G.gid[t] = f;
  }
  return G;
}
constexpr Groups kG = build_groups();
constexpr int NG = kG.ng;

// sort term indices by group (counting sort)
struct Sorted { int gstart[NG + 1]; int tidx[MAXT]; };
constexpr Sorted build_sorted() {
  Sorted S {};
  int cnt[MAXT] {};
  for (int t = 0; t < NT; ++t) cnt[kG.gid[t]] = cnt[kG.gid[t]] + 1;
  int acc = 0;
  for (int g = 0; g < NG; ++g) { S.gstart[g] = acc; acc += cnt[g]; }
  S.gstart[NG] = acc;
  int pos[MAXT] {};
  for (int g = 0; g < NG; ++g) pos[g] = S.gstart[g];
  for (int t = 0; t < NT; ++t) {
    int g = kG.gid[t];
    S.tidx[pos[g]] = t;
    pos[g] = pos[g] + 1;
  }
  return S;
}
constexpr Sorted kS = build_sorted();

// constant data: per sorted term, weight masks + sign; per group, member range
struct PrepData { int gstart[NG + 1]; uint32_t cm[NT], sm[NT]; float sgn[NT]; };
constexpr PrepData build_prep() {
  PrepData P {};
  for (int g = 0; g <= NG; ++g) P.gstart[g] = kS.gstart[g];
  for (int s = 0; s < NT; ++s) {
    int t = kS.tidx[s];
    P.cm[s] = kTL.t[t].cmask;
    P.sm[s] = kTL.t[t].smask;
    P.sgn[s] = (float)kTL.t[t].sign;
  }
  return P;
}
__device__ __constant__ PrepData dPD = build_prep();

// ---------- monomial eval helpers (all masks compile-time) ----------
template<uint32_t SXM, uint32_t CXM, int J, bool HAVE>
__device__ __forceinline__ float prodf(float cur, const float (&sx)[NQ], const float (&cx)[NQ]) {
  if constexpr (J == NQ) {
    if constexpr (HAVE) return cur; else return 1.f;
  } else if constexpr ((SXM >> J) & 1u) {
    if constexpr (HAVE) return prodf<SXM, CXM, J + 1, true>(cur * sx[J], sx, cx);
    else                return prodf<SXM, CXM, J + 1, true>(sx[J], sx, cx);
  } else if constexpr ((CXM >> J) & 1u) {
    if constexpr (HAVE) return prodf<SXM, CXM, J + 1, true>(cur * cx[J], sx, cx);
    else                return prodf<SXM, CXM, J + 1, true>(cx[J], sx, cx);
  } else {
    return prodf<SXM, CXM, J + 1, HAVE>(cur, sx, cx);
  }
}

template<int Lo, int Hi>
__device__ __forceinline__ void evalg(const float* __restrict__ coefg,
                                      const float (&sx)[NQ], const float (&cx)[NQ],
                                      float (&acc)[NQ]) {
  if constexpr (Hi - Lo == 1) {
    constexpr int w = kG.wire[Lo];
    float p = prodf<kG.sxm[Lo], kG.cxm[Lo], 0, false>(0.f, sx, cx);
    acc[w] = __builtin_fmaf(coefg[Lo], p, acc[w]);
  } else {
    constexpr int Mid = Lo + (Hi - Lo) / 2;
    evalg<Lo, Mid>(coefg, sx, cx, acc);
    evalg<Mid, Hi>(coefg, sx, cx, acc);
  }
}

// ---------- single fused kernel ----------
__global__ __launch_bounds__(TPB) void quanv_fused(
    const float* __restrict__ x, const float* __restrict__ w,
    float* __restrict__ out)
{
  __shared__ float wtc[NW], wts[NW];       // weight cos/sin
  __shared__ float tprod[NT];              // per-term products
  __shared__ float lcoef[NG];              // merged group coefficients
  __shared__ float red[SPB][CCH][NQ + 1];

  const int tid = threadIdx.x;

  // ---- phase 0: weight trig into LDS (18 threads)
  if (tid < NW) {
    float s, c;
    sincosf(w[tid], &s, &c);               // full angle, precise
    wts[tid] = s; wtc[tid] = c;
  }

  // ---- phase 2 (overlapped): per-(channel,site) pixel trig
  const int sl   = tid & (SPB - 1);        // site within block
  const int c    = tid >> 5;               // channel 0..7
  const int site = blockIdx.x * SPB + sl;
  const bool valid = site < NSITES;
  const int ho = site / WO;
  const int wo = site - ho * WO;

  float sx[NQ], cx[NQ];
  if (valid) {
    const float* xp = x + c * (HIMG * WIMG) + ho * WIMG + wo;
#pragma unroll
    for (int m = 0; m < NQ; ++m)
      __sincosf(3.14159265358979323846f * xp[(m / 3) * WIMG + (m % 3)], &sx[m], &cx[m]);
  } else {
#pragma unroll
    for (int m = 0; m < NQ; ++m) { sx[m] = 0.f; cx[m] = 0.f; }
  }

  __syncthreads();   // wtrig ready

  // ---- phase 1a: one thread per TERM, set-bit product via LDS-indexed factors
  for (int t = tid; t < NT; t += TPB) {
    float p = dPD.sgn[t];
    uint32_t cm = dPD.cm[t];
    while (cm) {
      int k = __ffs(cm) - 1;
      p *= wtc[k];
      cm &= cm - 1u;
    }
    uint32_t sm = dPD.sm[t];
    while (sm) {
      int k = __ffs(sm) - 1;
      p *= wts[k];
      sm &= sm - 1u;
    }
    tprod[t] = p;
  }
  __syncthreads();   // tprod ready

  // ---- phase 1b: one thread per GROUP, ordered (deterministic) member sum
  for (int g = tid; g < NG; g += TPB) {
    const int t0 = dPD.gstart[g], t1 = dPD.gstart[g + 1];
    float s = 0.f;
    for (int t = t0; t < t1; ++t) s += tprod[t];
    lcoef[g] = s;
  }
  __syncthreads();   // lcoef ready

  // ---- phase 3: static monomial eval (coefs broadcast from LDS)
  float acc[NQ];
#pragma unroll
  for (int q = 0; q < NQ; ++q) acc[q] = 0.f;
  evalg<0, NG>(lcoef, sx, cx, acc);

#pragma unroll
  for (int q = 0; q < NQ; ++q) red[sl][c][q] = acc[q];
  __syncthreads();

  // ---- phase 4: channel-sum and store
  for (int idx = tid; idx < SPB * NQ; idx += TPB) {
    int s2 = idx / NQ;
    int q  = idx - s2 * NQ;
    int gs = blockIdx.x * SPB + s2;
    if (gs < NSITES) {
      float s = 0.f;
#pragma unroll
      for (int cc = 0; cc < CCH; ++cc) s += red[s2][cc][q];
      out[gs * NQ + q] = s;      // raw reshape (Ho,Wo,9) -> flat
    }
  }
}

extern "C" void kernel_launch(void* const* d_in, const int* in_sizes, int n_in,
                              void* d_out, int out_size, void* d_ws, size_t ws_size,
                              hipStream_t stream)
{
  const float* x = (const float*)d_in[0];   // (1,8,128,128) f32
  const float* w = (const float*)d_in[1];   // (2,9) f32
  float* out = (float*)d_out;               // (9*126*126) f32

  const int blocks = (NSITES + SPB - 1) / SPB;
  quanv_fused<<<blocks, TPB, 0, stream>>>(x, w, out);
}

// Round 10
// 9.398 us; speedup vs baseline: 1.2879x; 1.2879x over previous
//
#include <hip/hip_runtime.h>
#include <stdint.h>

#define NQ     9
#define NW     18
#define HIMG   128
#define WIMG   128
#define HO     126
#define WO     126
#define CCH    8
#define NSITES (HO * WO)
#define MAXRAW 64
#define MAXT   4096
#define SPB    32          // sites per block
#define TPB    256         // 32 sites x 8 channels

struct Op { int type, a, b, widx; };     // 0=RX 1=RY 2=RZ 3=CNOT(a=ctrl,b=tgt)
struct OpList { int n; Op ops[MAXRAW]; };

// ---------- constexpr numpy legacy RandomState(42) (bit-exact, verified R1-R9) ----------
struct MTc {
  uint32_t key[624] {};
  int pos = 624;
  constexpr void seed(uint32_t s) {
    for (int i = 0; i < 624; ++i) {
      key[i] = s;
      s = 1812433253u * (s ^ (s >> 30)) + (uint32_t)i + 1u;
    }
    pos = 624;
  }
  constexpr uint32_t next32() {
    if (pos == 624) {
      for (int i = 0; i < 624; ++i) {
        uint32_t y = (key[i] & 0x80000000u) | (key[(i + 1) % 624] & 0x7fffffffu);
        key[i] = key[(i + 397) % 624] ^ (y >> 1) ^ ((y & 1u) ? 0x9908b0dfu : 0u);
      }
      pos = 0;
    }
    uint32_t y = key[pos++];
    y ^= y >> 11;
    y ^= (y << 7)  & 0x9d2c5680u;
    y ^= (y << 15) & 0xefc60000u;
    y ^= y >> 18;
    return y;
  }
  constexpr double rnd() {
    uint32_t a = next32() >> 5, b = next32() >> 6;
    return (a * 67108864.0 + b) / 9007199254740992.0;
  }
  constexpr uint32_t bounded32(uint32_t rng) {
    if (rng == 0) return 0;
    uint32_t mask = rng;
    mask |= mask >> 1;  mask |= mask >> 2;  mask |= mask >> 4;
    mask |= mask >> 8;  mask |= mask >> 16;
    uint32_t v = next32() & mask;
    while (v > rng) v = next32() & mask;
    return v;
  }
};

constexpr OpList build_ops() {
  OpList ol {};
  ol.n = 0;
  MTc mt {};
  mt.seed(42u);
  for (int l = 0; l < 2; ++l) {
    int i = 0;
    while (i < NQ) {
      if (mt.rnd() > 0.3) {
        int g  = (int)mt.bounded32(2);
        int wq = (int)mt.bounded32(8);
        if (ol.n < MAXRAW) { ol.ops[ol.n] = Op{g, wq, 0, l * NQ + i}; ol.n++; }
        ++i;
      } else {
        int arr[NQ] {};
        for (int t = 0; t < NQ; ++t) arr[t] = t;
        for (int k = NQ - 1; k >= 1; --k) {
          int j = (int)mt.bounded32((uint32_t)k);
          int tmp = arr[k]; arr[k] = arr[j]; arr[j] = tmp;
        }
        if (ol.n < MAXRAW) { ol.ops[ol.n] = Op{3, arr[0], arr[1], 0}; ol.n++; }
      }
    }
  }
  return ol;
}

// ---------- compile-time Heisenberg back-propagation of Z_w (verified R6-R9) ----------
struct Term { uint32_t cmask, smask, sxm, cxm; int wire, sign; };
struct TermList { int n; Term t[MAXT]; };

constexpr int kCNc[4][4] = {{0,0,3,3},{1,1,2,2},{2,2,1,1},{3,3,0,0}};
constexpr int kCNt[4][4] = {{0,1,2,3},{1,0,3,2},{1,0,3,2},{0,1,2,3}};
constexpr int kCNs[4][4] = {{1,1,1,1},{1,1,1,-1},{1,1,-1,1},{1,1,1,1}};
constexpr int kIAPn[4][4] = {{0,0,0,0},{0,0,3,2},{0,3,0,1},{0,2,1,0}};
constexpr int kIAPs[4][4] = {{0,0,0,0},{0,0,-1,1},{0,1,0,-1},{0,-1,1,0}};

constexpr void dfs(const OpList& raw, int k, uint32_t ty, int sg,
                   uint32_t cm, uint32_t sm, int wire, TermList& TL) {
  if (k < 0) {
    uint32_t sxm = 0, cxm = 0;
    for (int j = 0; j < NQ; ++j) {
      uint32_t p = (ty >> (2 * j)) & 3u;
      if (p == 2u) return;               // Y factor -> expectation 0, prune
      if (p == 1u) sxm |= 1u << j;
      if (p == 3u) cxm |= 1u << j;
    }
    if (TL.n < MAXT) {
      TL.t[TL.n].cmask = cm; TL.t[TL.n].smask = sm;
      TL.t[TL.n].sxm = sxm;  TL.t[TL.n].cxm = cxm;
      TL.t[TL.n].wire = wire; TL.t[TL.n].sign = sg;
    }
    TL.n = TL.n + 1;
    return;
  }
  Op op = raw.ops[k];
  if (op.type == 3) {
    uint32_t pc = (ty >> (2 * op.a)) & 3u;
    uint32_t pt = (ty >> (2 * op.b)) & 3u;
    uint32_t nty = ty & ~((3u << (2 * op.a)) | (3u << (2 * op.b)));
    nty |= (uint32_t)kCNc[pc][pt] << (2 * op.a);
    nty |= (uint32_t)kCNt[pc][pt] << (2 * op.b);
    dfs(raw, k - 1, nty, sg * kCNs[pc][pt], cm, sm, wire, TL);
  } else {
    int A = op.type + 1;
    uint32_t p = (ty >> (2 * op.a)) & 3u;
    if (p == 0u || p == (uint32_t)A) {
      dfs(raw, k - 1, ty, sg, cm, sm, wire, TL);
      return;
    }
    dfs(raw, k - 1, ty, sg, cm | (1u << op.widx), sm, wire, TL);
    uint32_t nty = (ty & ~(3u << (2 * op.a))) | ((uint32_t)kIAPn[A][p] << (2 * op.a));
    dfs(raw, k - 1, nty, sg * kIAPs[A][p], cm, sm | (1u << op.widx), wire, TL);
  }
}

constexpr TermList build_terms() {
  TermList TL {};
  OpList raw = build_ops();
  for (int w = 0; w < NQ; ++w)
    dfs(raw, raw.n - 1, 3u << (2 * w), 1, 0u, 0u, w, TL);
  return TL;
}

constexpr TermList kTL = build_terms();
static_assert(kTL.n <= MAXT, "Pauli term count exceeds MAXT - raise cap");
static_assert(kTL.n >= NQ, "must have at least one term per wire");
constexpr int NT = kTL.n;

// ---------- merge terms with identical final monomial (wire, sxm, cxm) ----------
struct Groups { int ng; int gid[MAXT]; int key[MAXT]; int wire[MAXT]; uint32_t sxm[MAXT], cxm[MAXT]; };
constexpr Groups build_groups() {
  Groups G {};
  for (int t = 0; t < NT; ++t) {
    int k = (kTL.t[t].wire << 18) | ((int)kTL.t[t].sxm << 9) | (int)kTL.t[t].cxm;
    int f = -1;
    for (int j = 0; j < G.ng; ++j)
      if (G.key[j] == k) { f = j; break; }
    if (f < 0) {
      f = G.ng;
      G.key[f] = k; G.wire[f] = kTL.t[t].wire;
      G.sxm[f] = kTL.t[t].sxm; G.cxm[f] = kTL.t[t].cxm;
      G.ng = G.ng + 1;
    }
    G.gid[t] = f;
  }
  return G;
}
constexpr Groups kG = build_groups();
constexpr int NG = kG.ng;

// sort term indices by group (counting sort)
struct Sorted { int gstart[NG + 1]; int tidx[MAXT]; };
constexpr Sorted build_sorted() {
  Sorted S {};
  int cnt[MAXT] {};
  for (int t = 0; t < NT; ++t) cnt[kG.gid[t]] = cnt[kG.gid[t]] + 1;
  int acc = 0;
  for (int g = 0; g < NG; ++g) { S.gstart[g] = acc; acc += cnt[g]; }
  S.gstart[NG] = acc;
  int pos[MAXT] {};
  for (int g = 0; g < NG; ++g) pos[g] = S.gstart[g];
  for (int t = 0; t < NT; ++t) {
    int g = kG.gid[t];
    S.tidx[pos[g]] = t;
    pos[g] = pos[g] + 1;
  }
  return S;
}
constexpr Sorted kS = build_sorted();

// prep-side constant data: per sorted term, weight masks + sign; per group, member range
struct PrepData { int gstart[NG + 1]; uint32_t cm[NT], sm[NT]; float sgn[NT]; };
constexpr PrepData build_prep() {
  PrepData P {};
  for (int g = 0; g <= NG; ++g) P.gstart[g] = kS.gstart[g];
  for (int s = 0; s < NT; ++s) {
    int t = kS.tidx[s];
    P.cm[s] = kTL.t[t].cmask;
    P.sm[s] = kTL.t[t].smask;
    P.sgn[s] = (float)kTL.t[t].sign;
  }
  return P;
}
__device__ __constant__ PrepData dPD = build_prep();

// ---------- monomial eval helpers (all masks compile-time) ----------
template<uint32_t SXM, uint32_t CXM, int J, bool HAVE>
__device__ __forceinline__ float prodf(float cur, const float (&sx)[NQ], const float (&cx)[NQ]) {
  if constexpr (J == NQ) {
    if constexpr (HAVE) return cur; else return 1.f;
  } else if constexpr ((SXM >> J) & 1u) {
    if constexpr (HAVE) return prodf<SXM, CXM, J + 1, true>(cur * sx[J], sx, cx);
    else                return prodf<SXM, CXM, J + 1, true>(sx[J], sx, cx);
  } else if constexpr ((CXM >> J) & 1u) {
    if constexpr (HAVE) return prodf<SXM, CXM, J + 1, true>(cur * cx[J], sx, cx);
    else                return prodf<SXM, CXM, J + 1, true>(cx[J], sx, cx);
  } else {
    return prodf<SXM, CXM, J + 1, HAVE>(cur, sx, cx);
  }
}

template<int Lo, int Hi>
__device__ __forceinline__ void evalg(const float* __restrict__ coefg,
                                      const float (&sx)[NQ], const float (&cx)[NQ],
                                      float (&acc)[NQ]) {
  if constexpr (Hi - Lo == 1) {
    constexpr int w = kG.wire[Lo];
    float p = prodf<kG.sxm[Lo], kG.cxm[Lo], 0, false>(0.f, sx, cx);
    acc[w] = __builtin_fmaf(coefg[Lo], p, acc[w]);
  } else {
    constexpr int Mid = Lo + (Hi - Lo) / 2;
    evalg<Lo, Mid>(coefg, sx, cx, acc);
    evalg<Mid, Hi>(coefg, sx, cx, acc);
  }
}

// ---------- single fused kernel (R8 structure; fast weight trig) ----------
__global__ __launch_bounds__(TPB) void quanv_fused(
    const float* __restrict__ x, const float* __restrict__ w,
    float* __restrict__ out)
{
  __shared__ float lcoef[NG];
  __shared__ float red[SPB][CCH][NQ + 1];

  const int tid  = threadIdx.x;

  // ---- phase 1: per-block redundant coefficient computation (one thread/group)
  if (tid < NG) {
    float wc[NW], ws[NW];
#pragma unroll
    for (int k = 0; k < NW; ++k) __sincosf(w[k], &ws[k], &wc[k]);   // HW trig, in-range args
    for (int g = tid; g < NG; g += TPB) {
      float c = 0.f;
      const int t0 = dPD.gstart[g], t1 = dPD.gstart[g + 1];
      for (int t = t0; t < t1; ++t) {
        float p = dPD.sgn[t];
        const uint32_t cm = dPD.cm[t], sm = dPD.sm[t];
#pragma unroll
        for (int k = 0; k < NW; ++k) {
          if ((cm >> k) & 1u) p *= wc[k];
          if ((sm >> k) & 1u) p *= ws[k];
        }
        c += p;
      }
      lcoef[g] = c;
    }
  }

  // ---- phase 2: per-(channel,site) pixel trig
  const int sl   = tid & (SPB - 1);        // site within block
  const int c    = tid >> 5;               // channel 0..7
  const int site = blockIdx.x * SPB + sl;
  const bool valid = site < NSITES;
  const int ho = site / WO;
  const int wo = site - ho * WO;

  float sx[NQ], cx[NQ];
  if (valid) {
    const float* xp = x + c * (HIMG * WIMG) + ho * WIMG + wo;
#pragma unroll
    for (int m = 0; m < NQ; ++m)
      __sincosf(3.14159265358979323846f * xp[(m / 3) * WIMG + (m % 3)], &sx[m], &cx[m]);
  } else {
#pragma unroll
    for (int m = 0; m < NQ; ++m) { sx[m] = 0.f; cx[m] = 0.f; }
  }

  __syncthreads();   // lcoef ready

  // ---- phase 3: static monomial eval (coefs broadcast from LDS)
  float acc[NQ];
#pragma unroll
  for (int q = 0; q < NQ; ++q) acc[q] = 0.f;
  evalg<0, NG>(lcoef, sx, cx, acc);

#pragma unroll
  for (int q = 0; q < NQ; ++q) red[sl][c][q] = acc[q];
  __syncthreads();

  // ---- phase 4: channel-sum and store
  for (int idx = tid; idx < SPB * NQ; idx += TPB) {
    int s2 = idx / NQ;
    int q  = idx - s2 * NQ;
    int gs = blockIdx.x * SPB + s2;
    if (gs < NSITES) {
      float s = 0.f;
#pragma unroll
      for (int cc = 0; cc < CCH; ++cc) s += red[s2][cc][q];
      out[gs * NQ + q] = s;      // raw reshape (Ho,Wo,9) -> flat
    }
  }
}

extern "C" void kernel_launch(void* const* d_in, const int* in_sizes, int n_in,
                              void* d_out, int out_size, void* d_ws, size_t ws_size,
                              hipStream_t stream)
{
  const float* x = (const float*)d_in[0];   // (1,8,128,128) f32
  const float* w = (const float*)d_in[1];   // (2,9) f32
  float* out = (float*)d_out;               // (9*126*126) f32

  const int blocks = (NSITES + SPB - 1) / SPB;
  quanv_fused<<<blocks, TPB, 0, stream>>>(x, w, out);
}